// Round 24
// baseline (52.879 us; speedup 1.0000x reference)
//
#include <hip/hip_runtime.h>

#define N_REAL 12
#define BATCH  4
#define CH     3
#define HH     256
#define WW     256
#define KK     4
#define TY     16                 // output rows per block (8 waves x 2 rows)
#define ROWST  19                 // TY + KK - 1 input rows
#define RSTR   256                // packed LDS row stride (dwords)
#define NTHR   512
#define HW     (HH * WW)
#define BUFSZ  (ROWST * RSTR)     // 4864 dwords per buffer

typedef float f32x4 __attribute__((ext_vector_type(4)));
typedef __attribute__((address_space(1))) const void gas_t;
typedef __attribute__((address_space(3))) void las_t;

// async global->LDS DMA: wave-uniform LDS base + lane*16B; one 256-dword row.
#define ASYNC_ROW16(gsrc, ldst) \
    __builtin_amdgcn_global_load_lds((gas_t*)(gsrc), (las_t*)(ldst), 16, 0, 0)

__device__ __forceinline__ float sigmoidf(float x) {
    float e = __builtin_amdgcn_exp2f(x * -1.44269504088896340736f);
    return __builtin_amdgcn_rcpf(1.0f + e);
}

// DPP wave shifts: bound_ctrl=1 -> out-of-wave lanes read 0 = image-edge pad.
__device__ __forceinline__ float dpp_shr1(float x) {   // lane i <- lane i-1
    return __int_as_float(__builtin_amdgcn_update_dpp(
        0, __float_as_int(x), 0x138 /*wave_shr:1*/, 0xf, 0xf, true));
}
__device__ __forceinline__ float dpp_shl1(float x) {   // lane i <- lane i+1
    return __int_as_float(__builtin_amdgcn_update_dpp(
        0, __float_as_int(x), 0x130 /*wave_shl:1*/, 0xf, 0xf, true));
}

__global__ __launch_bounds__(NTHR, 4)
void reverb_fused(const float* __restrict__ states,
                  const float* __restrict__ weights,
                  const float* __restrict__ bias,
                  float*       __restrict__ out)
{
    // LDS written ONLY by DMA; lanes never ds_write -> barrier needs vmcnt only.
    __shared__ __align__(16) float S[2][BUFSZ];   // 38.9 KB raw rows

    const int ty  = blockIdx.x;            // 0..15
    const int b   = blockIdx.y;            // batch
    const int v   = blockIdx.z;            // dest node
    const int tid = threadIdx.x;
    const int w   = tid >> 6;              // wave 0..7: owns output rows gy0+2w, 2w+1
    const int ln  = tid & 63;              // lane: owns cols 4ln..4ln+3
    const int gy0 = ty * TY;
    const int deg = (v == 0) ? 4 : 3;
    const int P   = 3 * deg;               // (edge,channel) phases

    // ---- staging metadata: wave w DMAs rows w, w+8, w+16 (r < 19) ----
    int  rr[3], goff[3];
    bool rvalid[3];
    #pragma unroll
    for (int k = 0; k < 3; ++k) {
        const int r = w + 8 * k;
        rr[k]     = r;
        rvalid[k] = (r < ROWST);           // wave-uniform
        const int gy  = gy0 + r - 1;       // SAME pad lo=1
        const int gyc = gy < 0 ? 0 : (gy > HH - 1 ? HH - 1 : gy);
        goff[k]  = gyc * WW + 4 * ln;
    }

    // ---- consume metadata: rows 2w+lr-1; OOB rows skipped (wave-uniform) ----
    bool crowok[5];
    #pragma unroll
    for (int lr = 0; lr < 5; ++lr)
        crowok[lr] = (unsigned)(gy0 + 2 * w - 1 + lr) < (unsigned)HH;

    // ---- edge tables (uniform) ----
    int ucA[4], eA[4];
    #pragma unroll
    for (int ei = 0; ei < 4; ++ei) {
        int t = v + 11 - ei; if (t >= 12) t -= 12;
        ucA[ei] = (ei == 3) ? 12 : t;
        eA[ei]  = (ei == 3) ? 36 : (ucA[ei] * 3 + ei);
    }

    float bsum[CH] = {0.f, 0.f, 0.f};
    for (int ei = 0; ei < deg; ++ei) {
        bsum[0] += bias[eA[ei] * CH + 0];
        bsum[1] += bias[eA[ei] * CH + 1];
        bsum[2] += bias[eA[ei] * CH + 2];
    }

    float acc[CH][2][4];
    #pragma unroll
    for (int co = 0; co < CH; ++co)
        #pragma unroll
        for (int yy = 0; yy < 2; ++yy)
            #pragma unroll
            for (int p = 0; p < 4; ++p) acc[co][yy][p] = 0.0f;

    // ---- prologue: DMA phase 0 into S[0] ----
    {
        const float* srcC0 = states + (size_t)(ucA[0] * BATCH + b) * CH * HW; // ci=0
        #pragma unroll
        for (int k = 0; k < 3; ++k)
            if (rvalid[k])
                ASYNC_ROW16(srcC0 + goff[k], &S[0][rr[k] * RSTR]);
        asm volatile("s_waitcnt vmcnt(0)" ::: "memory");
    }
    __builtin_amdgcn_s_barrier();

    for (int p = 0; p < P; ++p) {
        const int cur  = p & 1;
        const bool more = (p + 1 < P);

        // ---- issue next phase's DMA into the freed buffer (zero VGPR cost) ----
        if (more) {
            const int p1  = p + 1;
            const int ei1 = p1 / 3;
            const int ci1 = p1 - 3 * ei1;
            const float* srcC1 = states +
                (size_t)(ucA[ei1] * BATCH + b) * CH * HW + (size_t)ci1 * HW;
            #pragma unroll
            for (int k = 0; k < 3; ++k)
                if (rvalid[k])
                    ASYNC_ROW16(srcC1 + goff[k], &S[cur ^ 1][rr[k] * RSTR]);
        }

        // ---- compute phase p: ds_read raw -> sigmoid -> DPP halo -> FMA ----
        {
            const int ei = p / 3;
            const int ci = p - 3 * ei;
            const float* __restrict__ wbase = weights + eA[ei] * (CH * CH * KK * KK);
            #pragma unroll
            for (int lr = 0; lr < 5; ++lr) {
                if (!crowok[lr]) continue;            // wave-uniform (y pad -> 0)
                const float* rp = &S[cur][(2 * w + lr) * RSTR + 4 * ln];
                const f32x4 Rq = *(const f32x4*)rp;   // raw
                const float s0 = sigmoidf(Rq.x);
                const float s1 = sigmoidf(Rq.y);
                const float s2 = sigmoidf(Rq.z);
                const float s3 = sigmoidf(Rq.w);
                const float vv[7] = {dpp_shr1(s3),    // x-1 (lane0 -> 0)
                                     s0, s1, s2, s3,
                                     dpp_shl1(s0),    // x+4 (lane63 -> 0)
                                     dpp_shl1(s1)};   // x+5 (lane63 -> 0)
                #pragma unroll
                for (int yy = 0; yy < 2; ++yy) {
                    const int ky = lr - yy;
                    if (ky < 0 || ky > 3) continue;
                    #pragma unroll
                    for (int co = 0; co < CH; ++co) {
                        const f32x4 wv =
                            *(const f32x4*)(wbase + ((co * CH + ci) * KK + ky) * KK);
                        #pragma unroll
                        for (int pp = 0; pp < 4; ++pp) {
                            acc[co][yy][pp] = fmaf(wv.x, vv[pp + 0], acc[co][yy][pp]);
                            acc[co][yy][pp] = fmaf(wv.y, vv[pp + 1], acc[co][yy][pp]);
                            acc[co][yy][pp] = fmaf(wv.z, vv[pp + 2], acc[co][yy][pp]);
                            acc[co][yy][pp] = fmaf(wv.w, vv[pp + 3], acc[co][yy][pp]);
                        }
                    }
                }
            }
        }

        // ---- publish DMA(p+1): own loads drained, then raw barrier ----
        if (more) {
            asm volatile("s_waitcnt vmcnt(0)" ::: "memory");
            __builtin_amdgcn_s_barrier();   // no lgkm/full drain: lanes never ds_write
        }
    }

    const float inv = 1.0f / (float)deg;
    const size_t obase = (size_t)(v * BATCH + b) * CH * HW;
    #pragma unroll
    for (int co = 0; co < CH; ++co) {
        #pragma unroll
        for (int yy = 0; yy < 2; ++yy) {
            const int oy = gy0 + 2 * w + yy;
            f32x4 o;
            o.x = (acc[co][yy][0] + bsum[co]) * inv;
            o.y = (acc[co][yy][1] + bsum[co]) * inv;
            o.z = (acc[co][yy][2] + bsum[co]) * inv;
            o.w = (acc[co][yy][3] + bsum[co]) * inv;
            __builtin_nontemporal_store(o,
                (f32x4*)&out[obase + (size_t)co * HW + (size_t)oy * WW + 4 * ln]);
        }
    }
}

extern "C" void kernel_launch(void* const* d_in, const int* in_sizes, int n_in,
                              void* d_out, int out_size, void* d_ws, size_t ws_size,
                              hipStream_t stream)
{
    const float* states  = (const float*)d_in[0];
    const float* weights = (const float*)d_in[1];
    const float* bias    = (const float*)d_in[2];
    float*       out     = (float*)d_out;

    dim3 grid(HH / TY, BATCH, N_REAL);     // 16 x 4 x 12 = 768 blocks = 3/CU resident
    reverb_fused<<<grid, NTHR, 0, stream>>>(states, weights, bias, out);
}